// Round 10
// baseline (4994.896 us; speedup 1.0000x reference)
//
#include <hip/hip_runtime.h>
#include <hip/hip_bf16.h>
#include <stdint.h>

// HadLinear: out = blockFWHT1024(x)/32 @ W^T  ==  x @ (blockFWHT1024(W rows)/32)^T
// (1) x f32->bf16, (2) Wh = FWHT(W)/32 -> bf16, (3) bf16 MFMA GEMM.
// GEMM R10 = R4 schedule (single barrier/phase, reads post-barrier, VMC(2)
// post-MFMA at buffer boundaries) with BK=32 -> 64 KiB LDS -> 2 blocks/CU
// (TLP: the other block's MFMA fills this block's barrier/vmcnt stalls).
// 4 phases per 2 K-tiles; 1-issue-per-wave staging units (A groups, B halves).

typedef __attribute__((ext_vector_type(8))) short    short8;
typedef __attribute__((ext_vector_type(4))) float    f32x4;
typedef __attribute__((ext_vector_type(8))) uint16_t u16x8;

static constexpr int MDIM = 16384;
static constexpr int NDIM = 4096;
static constexpr int KDIM = 4096;
static constexpr int BM = 256, BN = 256, BK = 32;
static constexpr int NT = KDIM / BK;   // 128 K-tiles, 64 iterations

__device__ __forceinline__ uint16_t f2bf(float f) {
  union { float f; uint32_t u; } c; c.f = f;
  uint32_t u = c.u;
  return (uint16_t)((u + 0x7FFFu + ((u >> 16) & 1u)) >> 16);
}

__global__ __launch_bounds__(256) void cvt_x_kernel(const float* __restrict__ x,
                                                    uint16_t* __restrict__ xb, int n8) {
  int stride = gridDim.x * blockDim.x;
  for (int t = blockIdx.x * blockDim.x + threadIdx.x; t < n8; t += stride) {
    const float4* p = reinterpret_cast<const float4*>(x + (size_t)t * 8);
    float4 a = p[0], b = p[1];
    u16x8 o;
    o[0] = f2bf(a.x); o[1] = f2bf(a.y); o[2] = f2bf(a.z); o[3] = f2bf(a.w);
    o[4] = f2bf(b.x); o[5] = f2bf(b.y); o[6] = f2bf(b.z); o[7] = f2bf(b.w);
    *reinterpret_cast<u16x8*>(xb + (size_t)t * 8) = o;
  }
}

__global__ __launch_bounds__(256) void fwht_w_kernel(const float* __restrict__ W,
                                                     uint16_t* __restrict__ Wh) {
  __shared__ float s[1024];
  const int tid = threadIdx.x;
  const size_t base = (size_t)blockIdx.x * 1024;
  reinterpret_cast<float4*>(s)[tid] = reinterpret_cast<const float4*>(W + base)[tid];
  __syncthreads();
  for (int h = 1; h < 1024; h <<= 1) {
    #pragma unroll
    for (int pp = 0; pp < 2; ++pp) {
      int p = tid + pp * 256;
      int q = p & (h - 1);
      int i = ((p - q) << 1) | q;
      float a = s[i], b = s[i + h];
      s[i] = a + b;
      s[i + h] = a - b;
    }
    __syncthreads();
  }
  #pragma unroll
  for (int pp = 0; pp < 4; ++pp) {
    int i = tid + pp * 256;
    Wh[base + i] = f2bf(s[i] * 0.03125f);
  }
}

// ---------------- 4-phase GEMM: C[M,N] = A[M,K] * B[N,K]^T ----------------
// LDS tile: 256 rows x 4 chunks(16B), chunk (r,c') holds global c = c'^((r>>1)&3).
// Staging writes linearly per wave (16 rows/issue); source pre-swizzled.

#define FENCE asm volatile("" ::: "memory")
#define SBAR  do { FENCE; __builtin_amdgcn_s_barrier(); \
                   __builtin_amdgcn_sched_barrier(0); } while (0)
#define LGKM0 do { asm volatile("s_waitcnt lgkmcnt(0)" ::: "memory"); \
                   __builtin_amdgcn_sched_barrier(0); } while (0)
#define VMC(n) do { asm volatile("s_waitcnt vmcnt(" #n ")" ::: "memory"); \
                    __builtin_amdgcn_sched_barrier(0); } while (0)

#define LDA4(DST, BUF, MLO)                                                    \
  do { _Pragma("unroll")                                                       \
    for (int m_ = 0; m_ < 4; ++m_)                                             \
      DST[m_] = *(const short8*)(aRd + (BUF)*16384 + ((MLO)+m_)*1024 + koff);  \
  } while (0)

#define LDB4(DST, BUF)                                                         \
  do { _Pragma("unroll")                                                       \
    for (int n_ = 0; n_ < 4; ++n_)                                             \
      DST[n_] = *(const short8*)(bRd + (BUF)*16384 + n_*1024 + koff);          \
  } while (0)

#define MF16(AF, BF, MB)                                                       \
  do { __builtin_amdgcn_s_setprio(1);                                          \
    _Pragma("unroll")                                                          \
    for (int m_ = 0; m_ < 4; ++m_)                                             \
      _Pragma("unroll")                                                        \
      for (int n_ = 0; n_ < 4; ++n_)                                           \
        acc[(MB)+m_][n_] = __builtin_amdgcn_mfma_f32_16x16x32_bf16(            \
            AF[m_], BF[n_], acc[(MB)+m_][n_], 0, 0, 0);                        \
    __builtin_amdgcn_s_setprio(0);                                             \
  } while (0)

// Iteration i: tile 2i (buf0, ph1-2), T1=2i+1 (buf1, ph3-4).
// Staging units (1 global_load_lds per wave each): A group g = rows
// {g*64+0..63, g*64+128..191} (g0 = aL rows, g1 = aH rows); B half h = rows
// {h*128..h*128+127}.  Plan (2 units/phase):
//  ph1 T1.Ag1+T1.Bh1 | ph2 T2.Ag0+T2.Bh0 | ph3 T2.Ag1+T2.Bh1 | ph4 T3.Ag0+T3.Bh0
// vmcnt ledger: enter ph1 with 2 (T1.Ag0/Bh0 from prev ph4); ph1->4, ph2->6,
//  VMC(2) drains T1's 4 -> ph3 reads buf1 safe; ph3->4, ph4->6, VMC(2) drains
//  T2's 4 -> next ph1 reads buf0 safe.  WAR per phase: ph1 targets buf1 aH/Bh1
//  (read prev ph4/ph3) | ph2 buf0 aL+B (read ph1) | ph3 buf0 aH (ph2), Bh1
//  (ph1) | ph4 buf1 aL+B (read ph3).  All drained via LGKM0-before-MFMA + SBAR.
#define ITER(T1, T2, T3, FIN)                                                  \
  do {                                                                         \
    short8 aL[4], aH[4], bK[4];                                                \
    /* ph1: buf0 lower */ SBAR;                                                \
    LDB4(bK, 0); LDA4(aL, 0, 0);                                               \
    stageAg(1, 1, (T1)); stageBh(1, 1, (T1));                                  \
    LGKM0; MF16(aL, bK, 0);                                                    \
    /* ph2: buf0 upper */ SBAR;                                                \
    LDA4(aH, 0, 4);                                                            \
    if (!(FIN)) { stageAg(0, 0, (T2)); stageBh(0, 0, (T2)); }                  \
    LGKM0; MF16(aH, bK, 4);                                                    \
    if (FIN) { VMC(0); } else { VMC(2); }                                      \
    /* ph3: buf1 lower */ SBAR;                                                \
    LDB4(bK, 1); LDA4(aL, 1, 0);                                               \
    if (!(FIN)) { stageAg(0, 1, (T2)); stageBh(0, 1, (T2)); }                  \
    LGKM0; MF16(aL, bK, 0);                                                    \
    /* ph4: buf1 upper */ SBAR;                                                \
    LDA4(aH, 1, 4);                                                            \
    if (!(FIN)) { stageAg(1, 0, (T3)); stageBh(1, 0, (T3)); }                  \
    LGKM0; MF16(aH, bK, 4);                                                    \
    if (!(FIN)) { VMC(2); }                                                    \
  } while (0)

__global__ __launch_bounds__(512, 4) void gemm_bt(const uint16_t* __restrict__ A,
                                                  const uint16_t* __restrict__ B,
                                                  float* __restrict__ C) {
  __shared__ __align__(16) uint16_t Ab[2][BM * BK];   // 2 x 16 KiB
  __shared__ __align__(16) uint16_t Bb[2][BN * BK];   // 2 x 16 KiB  (64 KiB)

  const int tid = threadIdx.x;
  const int wv  = tid >> 6;
  const int l   = tid & 63;

  // XCD-aware mapping, per-XCD concurrent set ~= 8tm x 8tn (2 blocks/CU)
  const int xcd = blockIdx.x & 7;
  const int r_  = blockIdx.x >> 3;
  const int tm  = xcd * 8 + ((r_ & 31) >> 2);   // 64 M-tiles
  const int tn  = (r_ >> 5) * 4 + (r_ & 3);     // 16 N-tiles
  const int wm  = wv >> 2;          // 0..1 -> rows wm*128
  const int wn  = wv & 3;           // 0..3 -> cols wn*64

  // ---- staging sources (inverse-swizzled global), 1 issue/wave/unit ----
  // lane l covers row +(l>>2), chunk c' = l&3; src chunk c = (l&3)^((l>>3)&3)
  const int lr   = l >> 2;
  const int swz  = (l & 3) ^ ((l >> 3) & 3);
  // A: wave wv covers rows g*64 + (wv>>2)*128 + (wv&3)*16 + lr
  const uint16_t* sAg = A + (size_t)(tm * BM + (wv >> 2) * 128 + (wv & 3) * 16 + lr) * KDIM + swz * 8;
  // B: wave wv covers rows h*128 + wv*16 + lr
  const uint16_t* sBw = B + (size_t)(tn * BN + wv * 16 + lr) * KDIM + swz * 8;
  char* aDst = (char*)&Ab[0][0] + (wv >> 2) * 8192 + (wv & 3) * 1024;
  char* bDst = (char*)&Bb[0][0] + wv * 1024;

  auto stageAg = [&](int buf, int g, int tk) {
    __builtin_amdgcn_global_load_lds(
        (const __attribute__((address_space(1))) unsigned int*)
            (sAg + (size_t)(g * 64) * KDIM + tk * BK),
        (__attribute__((address_space(3))) unsigned int*)(aDst + buf * 16384 + g * 4096),
        16, 0, 0);
  };
  auto stageBh = [&](int buf, int half, int tk) {
    __builtin_amdgcn_global_load_lds(
        (const __attribute__((address_space(1))) unsigned int*)
            (sBw + (size_t)(half * 128) * KDIM + tk * BK),
        (__attribute__((address_space(3))) unsigned int*)(bDst + buf * 16384 + half * 8192),
        16, 0, 0);
  };

  // ---- swizzled ds_read bases (row stride 64 B, 4 chunks) ----
  const int lA = l & 15, hi = l >> 4;          // hi = logical k-chunk 0..3
  const int koff = (hi ^ ((lA >> 1) & 3)) * 16;
  const char* aRd = (const char*)&Ab[0][0] + (wm * 128 + lA) * 64;
  const char* bRd = (const char*)&Bb[0][0] + (wn * 64 + lA) * 64;

  f32x4 acc[8][4] = {};

  // ---- prologue: T0 full (4 units) + T1.Ag0 + T1.Bh0 ----
  stageAg(0, 0, 0); stageAg(0, 1, 0); stageBh(0, 0, 0); stageBh(0, 1, 0);
  stageAg(1, 0, 1); stageBh(1, 0, 1);
  VMC(2);            // own T0 loads landed; T1's 2 in flight
                     // (ph1's SBAR syncs all waves before first buf0 read)

  #pragma unroll 1
  for (int i = 0; i < NT / 2 - 1; ++i)     // i = 0..62
    ITER(2 * i + 1, 2 * i + 2, 2 * i + 3, 0);
  ITER(NT - 1, 0, 0, 1);                   // final iteration (tiles 126,127)

  // ---- epilogue: C/D layout col = lane&15, row = (lane>>4)*4 + j ----
  float* Cp = C + (size_t)(tm * BM + wm * 128) * NDIM + tn * BN + wn * 64;
  const int co = hi * 4;
  #pragma unroll
  for (int m = 0; m < 8; ++m)
    #pragma unroll
    for (int n = 0; n < 4; ++n)
      #pragma unroll
      for (int j = 0; j < 4; ++j)
        Cp[(size_t)(m * 16 + co + j) * NDIM + n * 16 + lA] = acc[m][n][j];
}

extern "C" void kernel_launch(void* const* d_in, const int* in_sizes, int n_in,
                              void* d_out, int out_size, void* d_ws, size_t ws_size,
                              hipStream_t stream) {
  (void)in_sizes; (void)n_in; (void)out_size; (void)ws_size;
  const float* x = (const float*)d_in[0];   // (4,4096,4096) f32
  const float* w = (const float*)d_in[1];   // (4096,4096) f32
  float* out = (float*)d_out;               // (4,4096,4096) f32

  uint16_t* xb = (uint16_t*)d_ws;                       // 128 MiB
  uint16_t* wh = xb + (size_t)MDIM * KDIM;              // 32 MiB

  cvt_x_kernel<<<2048, 256, 0, stream>>>(x, xb, (int)((MDIM * (size_t)KDIM) / 8));
  fwht_w_kernel<<<(NDIM * KDIM) / 1024, 256, 0, stream>>>(w, wh);
  gemm_bt<<<(MDIM / BM) * (NDIM / BN), 512, 0, stream>>>(xb, wh, out);
}

// Round 11
// 656.402 us; speedup vs baseline: 7.6095x; 7.6095x over previous
//
#include <hip/hip_runtime.h>
#include <hip/hip_bf16.h>
#include <stdint.h>

// HadLinear: out = blockFWHT1024(x)/32 @ W^T  ==  x @ (blockFWHT1024(W rows)/32)^T
// (1) x f32->bf16, (2) Wh = FWHT(W)/32 -> bf16, (3) bf16 MFMA GEMM.
// GEMM R11: TLP via 2 blocks/CU with register-budgeted geometry.
//   BM=256, BN=128, BK=32, 8 waves (4Mx2N, wave tile 64x64, acc=64 regs).
//   3-buffer LDS ring (72 KiB) -> 2 blocks/CU; phase t reads buf[t%3],
//   stages tile t+2 (3 gloads/wave) into buf[(t+2)%3]; VMC(3) post-MFMA.
//   Phase unit = R4-proven {SBAR; reads; stages; LGKM0; 16 MFMA; VMC}.

typedef __attribute__((ext_vector_type(8))) short    short8;
typedef __attribute__((ext_vector_type(4))) float    f32x4;
typedef __attribute__((ext_vector_type(8))) uint16_t u16x8;

static constexpr int MDIM = 16384;
static constexpr int NDIM = 4096;
static constexpr int KDIM = 4096;
static constexpr int BM = 256, BN = 128, BK = 32;
static constexpr int NT = KDIM / BK;   // 128 K-tiles (= phases)

__device__ __forceinline__ uint16_t f2bf(float f) {
  union { float f; uint32_t u; } c; c.f = f;
  uint32_t u = c.u;
  return (uint16_t)((u + 0x7FFFu + ((u >> 16) & 1u)) >> 16);
}

__global__ __launch_bounds__(256) void cvt_x_kernel(const float* __restrict__ x,
                                                    uint16_t* __restrict__ xb, int n8) {
  int stride = gridDim.x * blockDim.x;
  for (int t = blockIdx.x * blockDim.x + threadIdx.x; t < n8; t += stride) {
    const float4* p = reinterpret_cast<const float4*>(x + (size_t)t * 8);
    float4 a = p[0], b = p[1];
    u16x8 o;
    o[0] = f2bf(a.x); o[1] = f2bf(a.y); o[2] = f2bf(a.z); o[3] = f2bf(a.w);
    o[4] = f2bf(b.x); o[5] = f2bf(b.y); o[6] = f2bf(b.z); o[7] = f2bf(b.w);
    *reinterpret_cast<u16x8*>(xb + (size_t)t * 8) = o;
  }
}

__global__ __launch_bounds__(256) void fwht_w_kernel(const float* __restrict__ W,
                                                     uint16_t* __restrict__ Wh) {
  __shared__ float s[1024];
  const int tid = threadIdx.x;
  const size_t base = (size_t)blockIdx.x * 1024;
  reinterpret_cast<float4*>(s)[tid] = reinterpret_cast<const float4*>(W + base)[tid];
  __syncthreads();
  for (int h = 1; h < 1024; h <<= 1) {
    #pragma unroll
    for (int pp = 0; pp < 2; ++pp) {
      int p = tid + pp * 256;
      int q = p & (h - 1);
      int i = ((p - q) << 1) | q;
      float a = s[i], b = s[i + h];
      s[i] = a + b;
      s[i + h] = a - b;
    }
    __syncthreads();
  }
  #pragma unroll
  for (int pp = 0; pp < 4; ++pp) {
    int i = tid + pp * 256;
    Wh[base + i] = f2bf(s[i] * 0.03125f);
  }
}

// ---------------- GEMM: C[M,N] = A[M,K] * B[N,K]^T ----------------
// LDS tile: rows x 4 chunks(16B); chunk (r,c') holds global c = c'^((r>>1)&3).
// Bank check (64B rows): 64 lanes -> 2 lanes/bank (free, m136).

#define FENCE asm volatile("" ::: "memory")
#define SBAR  do { FENCE; __builtin_amdgcn_s_barrier(); \
                   __builtin_amdgcn_sched_barrier(0); } while (0)
#define LGKM0 do { asm volatile("s_waitcnt lgkmcnt(0)" ::: "memory"); \
                   __builtin_amdgcn_sched_barrier(0); } while (0)
#define VMC(n) do { asm volatile("s_waitcnt vmcnt(" #n ")" ::: "memory"); \
                    __builtin_amdgcn_sched_barrier(0); } while (0)

#define LDA4(DST, BUF)                                                         \
  do { _Pragma("unroll")                                                       \
    for (int m_ = 0; m_ < 4; ++m_)                                             \
      DST[m_] = *(const short8*)(aRd + (BUF)*16384 + m_*1024 + koff);          \
  } while (0)

#define LDB4(DST, BUF)                                                         \
  do { _Pragma("unroll")                                                       \
    for (int n_ = 0; n_ < 4; ++n_)                                             \
      DST[n_] = *(const short8*)(bRd + (BUF)*8192 + n_*1024 + koff);           \
  } while (0)

#define MF16(AF, BF)                                                           \
  do { __builtin_amdgcn_s_setprio(1);                                          \
    _Pragma("unroll")                                                          \
    for (int m_ = 0; m_ < 4; ++m_)                                             \
      _Pragma("unroll")                                                        \
      for (int n_ = 0; n_ < 4; ++n_)                                           \
        acc[m_][n_] = __builtin_amdgcn_mfma_f32_16x16x32_bf16(                 \
            AF[m_], BF[n_], acc[m_][n_], 0, 0, 0);                             \
    __builtin_amdgcn_s_setprio(0);                                             \
  } while (0)

// Phase t: read buf RB=t%3, stage tile T2=t+2 into buf (t+2)%3.
// WAR: buf[(t+2)%3]'s last reads were phase t-1, drained (LGKM0) before any
// wave passed SBAR(t) -> stage-after-SBAR(t) is safe.
// vmcnt: enter with 6 (tiles t,t+1? -> t's 3 drained at t-1's VMC(3));
// stage +3 -> 6; VMC(3) drains tile t+1's 3 -> phase t+1 reads safe (all
// waves VMC before SBAR(t+1) -> every wave's slice landed).
#define PH(RB, STB, T2)                                                        \
  do {                                                                         \
    short8 aF[4], bF[4];                                                       \
    SBAR;                                                                      \
    LDB4(bF, RB); LDA4(aF, RB);                                                \
    stageA(STB, 0, (T2)); stageA(STB, 1, (T2)); stageB(STB, (T2));             \
    LGKM0; MF16(aF, bF);                                                       \
    VMC(3);                                                                    \
  } while (0)

__global__ __launch_bounds__(512, 4) void gemm_bt(const uint16_t* __restrict__ A,
                                                  const uint16_t* __restrict__ B,
                                                  float* __restrict__ C) {
  __shared__ __align__(16) uint16_t Ab[3][BM * BK];   // 3 x 16 KiB
  __shared__ __align__(16) uint16_t Bb[3][BN * BK];   // 3 x  8 KiB (72 KiB)

  const int tid = threadIdx.x;
  const int wv  = tid >> 6;
  const int l   = tid & 63;

  // XCD-bijective: 2048 blocks, per-XCD concurrent ~8tm x 8tn square.
  // b = (q*8 + xcd)*64 + s  ->  tm = xcd*8 + (s>>3), tn = q*8 + (s&7)
  const int xcd = blockIdx.x & 7;
  const int r_  = blockIdx.x >> 3;        // 0..255
  const int q_  = r_ >> 6;                // 0..3
  const int s_  = r_ & 63;
  const int tm  = xcd * 8 + (s_ >> 3);    // 64 M-tiles
  const int tn  = q_ * 8 + (s_ & 7);      // 32 N-tiles
  const int wm  = wv >> 1;                // 0..3 -> rows wm*64
  const int wn  = wv & 1;                 // 0..1 -> cols wn*64

  // ---- staging sources (inverse-swizzled global), 1 issue/wave/unit ----
  // thread tid covers row tid>>2 (A-half/B-tile local), chunk c' = tid&3;
  // src chunk c = (tid&3) ^ (((tid>>2)>>1)&3) = (tid&3)^((tid>>3)&3)
  const int lr   = l >> 2;
  const int swz  = (l & 3) ^ ((l >> 3) & 3);
  const uint16_t* sA = A + (size_t)(tm * BM + wv * 16 + lr) * KDIM + swz * 8;  // + h*128 rows
  const uint16_t* sB = B + (size_t)(tn * BN + wv * 16 + lr) * KDIM + swz * 8;
  char* aDstW = (char*)&Ab[0][0] + wv * 1024;
  char* bDstW = (char*)&Bb[0][0] + wv * 1024;

  auto stageA = [&](int buf, int h, int tk) {
    __builtin_amdgcn_global_load_lds(
        (const __attribute__((address_space(1))) unsigned int*)
            (sA + (size_t)(h * 128) * KDIM + tk * BK),
        (__attribute__((address_space(3))) unsigned int*)
            (aDstW + buf * 16384 + h * 8192),
        16, 0, 0);
  };
  auto stageB = [&](int buf, int tk) {
    __builtin_amdgcn_global_load_lds(
        (const __attribute__((address_space(1))) unsigned int*)
            (sB + (size_t)tk * BK),
        (__attribute__((address_space(3))) unsigned int*)
            (bDstW + buf * 8192),
        16, 0, 0);
  };

  // ---- swizzled ds_read bases (row stride 64 B) ----
  const int lA = l & 15, hi = l >> 4;              // hi = logical k-chunk
  const int koff = (hi ^ ((lA >> 1) & 3)) * 16;
  const char* aRd = (const char*)&Ab[0][0] + (wm * 64 + lA) * 64;
  const char* bRd = (const char*)&Bb[0][0] + (wn * 64 + lA) * 64;

  f32x4 acc[4][4] = {};

  // ---- prologue: T0 -> buf0, T1 -> buf1 (3 issues each) ----
  stageA(0, 0, 0); stageA(0, 1, 0); stageB(0, 0);
  stageA(1, 0, 1); stageA(1, 1, 1); stageB(1, 1);
  VMC(3);            // T0 landed (all waves sync at first SBAR before reading)

  #pragma unroll 1
  for (int i = 0; i < 42; ++i) {          // t = 3i, 3i+1, 3i+2  (0..125)
    PH(0, 2, 3 * i + 2);
    PH(1, 0, 3 * i + 3);
    PH(2, 1, 3 * i + 4);
  }
  // t = 126 (buf0): nothing to stage; drain T127 for the last phase.
  {
    short8 aF[4], bF[4];
    SBAR;
    LDB4(bF, 0); LDA4(aF, 0);
    LGKM0; MF16(aF, bF);
    VMC(0);
  }
  // t = 127 (buf1)
  {
    short8 aF[4], bF[4];
    SBAR;
    LDB4(bF, 1); LDA4(aF, 1);
    LGKM0; MF16(aF, bF);
  }

  // ---- epilogue: C/D layout col = lane&15, row = (lane>>4)*4 + j ----
  float* Cp = C + (size_t)(tm * BM + wm * 64) * NDIM + tn * BN + wn * 64;
  const int co = hi * 4;
  #pragma unroll
  for (int m = 0; m < 4; ++m)
    #pragma unroll
    for (int n = 0; n < 4; ++n)
      #pragma unroll
      for (int j = 0; j < 4; ++j)
        Cp[(size_t)(m * 16 + co + j) * NDIM + n * 16 + lA] = acc[m][n][j];
}

extern "C" void kernel_launch(void* const* d_in, const int* in_sizes, int n_in,
                              void* d_out, int out_size, void* d_ws, size_t ws_size,
                              hipStream_t stream) {
  (void)in_sizes; (void)n_in; (void)out_size; (void)ws_size;
  const float* x = (const float*)d_in[0];   // (4,4096,4096) f32
  const float* w = (const float*)d_in[1];   // (4096,4096) f32
  float* out = (float*)d_out;               // (4,4096,4096) f32

  uint16_t* xb = (uint16_t*)d_ws;                       // 128 MiB
  uint16_t* wh = xb + (size_t)MDIM * KDIM;              // 32 MiB

  cvt_x_kernel<<<2048, 256, 0, stream>>>(x, xb, (int)((MDIM * (size_t)KDIM) / 8));
  fwht_w_kernel<<<(NDIM * KDIM) / 1024, 256, 0, stream>>>(w, wh);
  gemm_bt<<<(MDIM / BM) * (NDIM / BN), 512, 0, stream>>>(xb, wh, out);
}

// Round 12
// 633.913 us; speedup vs baseline: 7.8795x; 1.0355x over previous
//
#include <hip/hip_runtime.h>
#include <hip/hip_bf16.h>
#include <stdint.h>

// HadLinear: out = blockFWHT1024(x)/32 @ W^T  ==  x @ (blockFWHT1024(W rows)/32)^T
// (1) x f32->bf16, (2) Wh = FWHT(W)/32 -> bf16, (3) bf16 MFMA GEMM.
// GEMM R12 = R4 skeleton (single barrier/phase, VMC(4) post-MFMA @ph4/ph8,
// 8 phases / 2 K-tiles, BM=BN=256, BK=64, 8 waves 2Mx4N, 2-buf LDS, XOR
// swizzle both-sides, R7 XCD map) with MFMA shape 32x32x16 (measured 2495 TF
// vs 2075 for 16x16x32 -> 0.83x MFMA-pipe time, same FLOPs/bytes/schedule).
// Wave tile 128x64 = 4mt x 2nt of 32x32; phase = 8 MFMA (2mt x 2nt x 2ks).

typedef __attribute__((ext_vector_type(8)))  short    short8;   // 8 bf16
typedef __attribute__((ext_vector_type(16))) float    f32x16;   // 32x32 C/D
typedef __attribute__((ext_vector_type(8)))  uint16_t u16x8;

static constexpr int MDIM = 16384;
static constexpr int NDIM = 4096;
static constexpr int KDIM = 4096;
static constexpr int BM = 256, BN = 256, BK = 64;
static constexpr int NT = KDIM / BK;   // 64 K-tiles, 32 iterations

__device__ __forceinline__ uint16_t f2bf(float f) {
  union { float f; uint32_t u; } c; c.f = f;
  uint32_t u = c.u;
  return (uint16_t)((u + 0x7FFFu + ((u >> 16) & 1u)) >> 16);
}

__global__ __launch_bounds__(256) void cvt_x_kernel(const float* __restrict__ x,
                                                    uint16_t* __restrict__ xb, int n8) {
  int stride = gridDim.x * blockDim.x;
  for (int t = blockIdx.x * blockDim.x + threadIdx.x; t < n8; t += stride) {
    const float4* p = reinterpret_cast<const float4*>(x + (size_t)t * 8);
    float4 a = p[0], b = p[1];
    u16x8 o;
    o[0] = f2bf(a.x); o[1] = f2bf(a.y); o[2] = f2bf(a.z); o[3] = f2bf(a.w);
    o[4] = f2bf(b.x); o[5] = f2bf(b.y); o[6] = f2bf(b.z); o[7] = f2bf(b.w);
    *reinterpret_cast<u16x8*>(xb + (size_t)t * 8) = o;
  }
}

__global__ __launch_bounds__(256) void fwht_w_kernel(const float* __restrict__ W,
                                                     uint16_t* __restrict__ Wh) {
  __shared__ float s[1024];
  const int tid = threadIdx.x;
  const size_t base = (size_t)blockIdx.x * 1024;
  reinterpret_cast<float4*>(s)[tid] = reinterpret_cast<const float4*>(W + base)[tid];
  __syncthreads();
  for (int h = 1; h < 1024; h <<= 1) {
    #pragma unroll
    for (int pp = 0; pp < 2; ++pp) {
      int p = tid + pp * 256;
      int q = p & (h - 1);
      int i = ((p - q) << 1) | q;
      float a = s[i], b = s[i + h];
      s[i] = a + b;
      s[i + h] = a - b;
    }
    __syncthreads();
  }
  #pragma unroll
  for (int pp = 0; pp < 4; ++pp) {
    int i = tid + pp * 256;
    Wh[base + i] = f2bf(s[i] * 0.03125f);
  }
}

// ---------------- 8-phase GEMM: C[M,N] = A[M,K] * B[N,K]^T ----------------
// LDS tile: 256 rows x 8 chunks(16B), chunk (r,c') holds global c = c'^((r>>1)&7).
// 32x32x16 frag: lane reads row (tile + l&31), 8 bf16 at k = ks*16 + (l>>5)*8
// -> logical chunk 2*ks + (l>>5); physical = logical ^ ((r>>1)&7) (lane-const).

#define FENCE asm volatile("" ::: "memory")
#define SBAR  do { FENCE; __builtin_amdgcn_s_barrier(); \
                   __builtin_amdgcn_sched_barrier(0); } while (0)
#define LGKM0 do { asm volatile("s_waitcnt lgkmcnt(0)" ::: "memory"); \
                   __builtin_amdgcn_sched_barrier(0); } while (0)
#define VMC(n) do { asm volatile("s_waitcnt vmcnt(" #n ")" ::: "memory"); \
                    __builtin_amdgcn_sched_barrier(0); } while (0)

// A frags for mt in {MLO, MLO+1}, ks-pair base KO (koff0 or koff0^64):
// DST[mi*2+ks] ; offsets: mt*32 rows = mt*4096 B; ks low/high = KO / KO^32.
#define LDA(DST, BUF, MLO, KO)                                                 \
  do { _Pragma("unroll")                                                       \
    for (int mi_ = 0; mi_ < 2; ++mi_)                                          \
      _Pragma("unroll")                                                        \
      for (int ks_ = 0; ks_ < 2; ++ks_)                                        \
        DST[mi_ * 2 + ks_] = *(const short8*)(aRd + (BUF)*32768 +              \
            ((MLO) + mi_) * 4096 + ((KO) ^ (ks_ ? 32 : 0)));                   \
  } while (0)

// B frags for nt in {0,1}: DST[ni*2+ks]
#define LDB(DST, BUF, KO)                                                      \
  do { _Pragma("unroll")                                                       \
    for (int ni_ = 0; ni_ < 2; ++ni_)                                          \
      _Pragma("unroll")                                                        \
      for (int ks_ = 0; ks_ < 2; ++ks_)                                        \
        DST[ni_ * 2 + ks_] = *(const short8*)(bRd + (BUF)*32768 +              \
            ni_ * 4096 + ((KO) ^ (ks_ ? 32 : 0)));                             \
  } while (0)

// 8 MFMA: mt {MB,MB+1} x nt {0,1} x ks {0,1}
#define MFQ(AF, BF, MB)                                                        \
  do { __builtin_amdgcn_s_setprio(1);                                          \
    _Pragma("unroll")                                                          \
    for (int ks_ = 0; ks_ < 2; ++ks_)                                          \
      _Pragma("unroll")                                                        \
      for (int mi_ = 0; mi_ < 2; ++mi_)                                        \
        _Pragma("unroll")                                                      \
        for (int ni_ = 0; ni_ < 2; ++ni_)                                      \
          acc[(MB)+mi_][ni_] = __builtin_amdgcn_mfma_f32_32x32x16_bf16(        \
              AF[mi_*2+ks_], BF[ni_*2+ks_], acc[(MB)+mi_][ni_], 0, 0, 0);      \
    __builtin_amdgcn_s_setprio(0);                                             \
  } while (0)

// Same phase regions as R4 (ph1 rows 0-63 + B 0-63 @k0; ph2 rows 64-127 @k0;
// ph3 k1 low; ph4 k1 high) -> all R4 stage/WAR proofs carry over unchanged.
// Stages: ph1 T1.A.g1 | ph2 T1.B.h1 | ph4 T2.B.h0+A.g0 | ph5 T2.A.g1
//         ph6 T2.B.h1 | ph8 T3.B.h0+A.g0.  VMC(4) post-MFMA @ph4/ph8.
#define ITER(T1, T2, T3, FIN)                                                  \
  do {                                                                         \
    short8 aF[4], bF[4];                                                       \
    /* ph1 */ SBAR;                                                            \
    LDB(bF, 0, koff0); LDA(aF, 0, 0, koff0);                                   \
    stageAg(1, 1, (T1));                                                       \
    LGKM0; MFQ(aF, bF, 0);                                                     \
    /* ph2 */ SBAR;                                                            \
    LDA(aF, 0, 2, koff0);                                                      \
    stageB(1, 1, (T1));                                                        \
    LGKM0; MFQ(aF, bF, 2);                                                     \
    /* ph3 */ SBAR;                                                            \
    LDB(bF, 0, koff0 ^ 64); LDA(aF, 0, 0, koff0 ^ 64);                         \
    LGKM0; MFQ(aF, bF, 0);                                                     \
    /* ph4 */ SBAR;                                                            \
    LDA(aF, 0, 2, koff0 ^ 64);                                                 \
    if (!(FIN)) { stageB(0, 0, (T2)); stageAg(0, 0, (T2)); }                   \
    LGKM0; MFQ(aF, bF, 2);                                                     \
    if (FIN) { VMC(0); } else { VMC(4); }                                      \
    /* ph5 */ SBAR;                                                            \
    LDB(bF, 1, koff0); LDA(aF, 1, 0, koff0);                                   \
    if (!(FIN)) stageAg(0, 1, (T2));                                           \
    LGKM0; MFQ(aF, bF, 0);                                                     \
    /* ph6 */ SBAR;                                                            \
    LDA(aF, 1, 2, koff0);                                                      \
    if (!(FIN)) stageB(0, 1, (T2));                                            \
    LGKM0; MFQ(aF, bF, 2);                                                     \
    /* ph7 */ SBAR;                                                            \
    LDB(bF, 1, koff0 ^ 64); LDA(aF, 1, 0, koff0 ^ 64);                         \
    LGKM0; MFQ(aF, bF, 0);                                                     \
    /* ph8 */ SBAR;                                                            \
    LDA(aF, 1, 2, koff0 ^ 64);                                                 \
    if (!(FIN)) { stageB(1, 0, (T3)); stageAg(1, 0, (T3)); }                   \
    LGKM0; MFQ(aF, bF, 2);                                                     \
    if (!(FIN)) { VMC(4); }                                                    \
  } while (0)

__global__ __launch_bounds__(512, 2) void gemm_bt(const uint16_t* __restrict__ A,
                                                  const uint16_t* __restrict__ B,
                                                  float* __restrict__ C) {
  __shared__ __align__(16) uint16_t Ab[2][BM * BK];   // 2 x 32 KiB
  __shared__ __align__(16) uint16_t Bb[2][BN * BK];   // 2 x 32 KiB

  const int tid = threadIdx.x;
  const int wv  = tid >> 6;
  const int l   = tid & 63;

  // XCD-aware mapping, per-XCD concurrent set = 8tm x 4tn (bijective)
  const int xcd = blockIdx.x & 7;
  const int r_  = blockIdx.x >> 3;
  const int tm  = xcd * 8 + ((r_ & 31) >> 2);   // 64 M-tiles
  const int tn  = (r_ >> 5) * 4 + (r_ & 3);     // 16 N-tiles
  const int wm  = wv >> 2;          // 0..1 -> rows wm*128
  const int wn  = wv & 3;           // 0..3 -> cols wn*64

  // ---- staging source (inverse-swizzled global) ----
  const int t8  = tid >> 3;
  const int swz = (tid & 7) ^ ((tid >> 4) & 7);
  const uint16_t* sA = A + (size_t)(tm * BM + t8) * KDIM + swz * 8;
  const uint16_t* sB = B + (size_t)(tn * BN + t8) * KDIM + swz * 8;

  // A read-group staging: g covers rows {g*64 + j*128 + 0..63}, j = 0,1
  auto stageAg = [&](int buf, int g, int tk) {
    #pragma unroll
    for (int j = 0; j < 2; ++j)
      __builtin_amdgcn_global_load_lds(
          (const __attribute__((address_space(1))) unsigned int*)
              (sA + (size_t)(g * 64 + j * 128) * KDIM + tk * BK),
          (__attribute__((address_space(3))) unsigned int*)
              ((char*)&Ab[buf][0] + g * 8192 + j * 16384 + wv * 1024),
          16, 0, 0);
  };
  auto stageB = [&](int buf, int half, int tk) {
    #pragma unroll
    for (int j = 0; j < 2; ++j)
      __builtin_amdgcn_global_load_lds(
          (const __attribute__((address_space(1))) unsigned int*)
              (sB + (size_t)(half * 128 + j * 64) * KDIM + tk * BK),
          (__attribute__((address_space(3))) unsigned int*)
              ((char*)&Bb[buf][0] + half * 16384 + j * 8192 + wv * 1024),
          16, 0, 0);
  };

  // ---- swizzled ds_read bases (32x32 frag addressing) ----
  const int l31 = l & 31, h32 = l >> 5;
  const int key = (l31 >> 1) & 7;
  const int koff0 = (h32 ^ key) * 16;               // ks0; ks1=^32, k1=^64
  const char* aRd = (const char*)&Ab[0][0] + (wm * 128 + l31) * 128;
  const char* bRd = (const char*)&Bb[0][0] + (wn * 64 + l31) * 128;

  f32x16 acc[4][2] = {};   // 4 mt x 2 nt of 32x32

  // ---- prologue: T0 full (8 loads) + T1.B.h0 + T1.A.g0 (4 loads) ----
  stageAg(0, 0, 0); stageAg(0, 1, 0); stageB(0, 0, 0); stageB(0, 1, 0);
  stageB(1, 0, 1);  stageAg(1, 0, 1);
  VMC(4);            // own T0 loads landed; T1's 4 in flight
                     // (ph1's SBAR syncs all waves before first buf0 read)

  #pragma unroll 1
  for (int i = 0; i < NT / 2 - 1; ++i)     // i = 0..30
    ITER(2 * i + 1, 2 * i + 2, 2 * i + 3, 0);
  ITER(NT - 1, 0, 0, 1);                   // final iteration

  // ---- epilogue: 32x32 C/D layout (m74/m101-verified):
  //      col = lane&31, row = (reg&3) + 8*(reg>>2) + 4*(lane>>5) ----
  float* Cp = C + (size_t)(tm * BM + wm * 128) * NDIM + tn * BN + wn * 64;
  #pragma unroll
  for (int mt = 0; mt < 4; ++mt)
    #pragma unroll
    for (int nt = 0; nt < 2; ++nt)
      #pragma unroll
      for (int rg = 0; rg < 16; ++rg) {
        int row = mt * 32 + (rg & 3) + 8 * (rg >> 2) + 4 * h32;
        Cp[(size_t)row * NDIM + nt * 32 + l31] = acc[mt][nt][rg];
      }
}

extern "C" void kernel_launch(void* const* d_in, const int* in_sizes, int n_in,
                              void* d_out, int out_size, void* d_ws, size_t ws_size,
                              hipStream_t stream) {
  (void)in_sizes; (void)n_in; (void)out_size; (void)ws_size;
  const float* x = (const float*)d_in[0];   // (4,4096,4096) f32
  const float* w = (const float*)d_in[1];   // (4096,4096) f32
  float* out = (float*)d_out;               // (4,4096,4096) f32

  uint16_t* xb = (uint16_t*)d_ws;                       // 128 MiB
  uint16_t* wh = xb + (size_t)MDIM * KDIM;              // 32 MiB

  cvt_x_kernel<<<2048, 256, 0, stream>>>(x, xb, (int)((MDIM * (size_t)KDIM) / 8));
  fwht_w_kernel<<<(NDIM * KDIM) / 1024, 256, 0, stream>>>(w, wh);
  gemm_bt<<<(MDIM / BM) * (NDIM / BN), 512, 0, stream>>>(xb, wh, out);
}